// Round 2
// baseline (219.256 us; speedup 1.0000x reference)
//
#include <hip/hip_runtime.h>

// CapsuleLayer dynamic routing, MI355X — recompute-u_hat design (no 189MB buffer).
// inputs [256,1152,8] f32, W [1152,10,8,16] f32, bias [1,1152,10,1] f32.
//
// Math restructure (agreement updates are linear in out):
//   pass r weights: c_r = softmax_c(bias + dot_v(u_hat, osum_{r-1})), osum_0 = 0
//   osum_r = out_1 + ... + out_r
//   s_r[b,c,v] = sum_i c_r[b,i,c] * u_hat[b,i,c,v];  out_r = squash_v(s_r)
// u_hat[b,i,c,v] = sum_d x[b,i,d] W[i,c,d,v] is recomputed per pass into LDS
// (755 MFLOP/pass ~ 5us of VALU vs 189MB/pass ~ 30us of HBM).

#define N_I   1152
#define N_C   10
#define N_B   256
#define CV    160     // N_C * 16
#define IC    8       // i per chunk
#define N_ICH 144     // 1152 / 8
#define BT    16      // b per block
#define BCH   8       // b per sub-chunk (2 chunks per block)
#define NBS   16      // b-splits (256/16)
#define UPAD  164     // padded c*v stride (+4 floats breaks bank alignment)

// grid 2304 = 144 i-chunks x 16 b-splits, block 320 = 8 i x 10 c x 4 vq
template <int MODE>  // 0: weights = softmax_c(bias) only; 1: + dot(u, osum)
__global__ __launch_bounds__(320, 4)
void k_pass(const float* __restrict__ inp, const float* __restrict__ W,
            const float* __restrict__ bias, const float* __restrict__ osum,
            float* __restrict__ s_part) {
    const int ic = blockIdx.x % N_ICH;
    const int bs = blockIdx.x / N_ICH;
    const int i0 = ic * IC;
    const int b0 = bs * BT;
    const int t  = threadIdx.x;

    __shared__ float u_tile[BCH * IC * UPAD];   // 41984 B
    __shared__ float xl[BCH * IC * 8];          //  2048 B
    __shared__ float osl[BCH * CV];             //  5120 B
    __shared__ float wt[BCH * IC * N_C];        //  2560 B

    // Phase-A lane identity: (iA, cA, vqA); also reused as B2's (bb, c2, vq2)
    const int iA  = t / 40;        // 0..7
    const int cA  = (t % 40) / 4;  // 0..9
    const int vqA = t % 4;
    // Phase-B1 lane identity (t < 256): (b1, i1, vq1)
    const int b1  = t >> 5;        // 0..7
    const int i1  = (t >> 2) & 7;  // 0..7
    const int vq1 = t & 3;

    // W fragment held in registers for the whole kernel: W[i0+iA][cA][d][vqA*4..+3]
    float4 Wr[8];
    {
        const float* wb = W + (size_t)(i0 + iA) * 1280 + cA * 128 + vqA * 4;
        #pragma unroll
        for (int d = 0; d < 8; ++d) Wr[d] = *(const float4*)(wb + d * 16);
    }

    // MODE 0: batch-independent weights w0[i] = softmax_c(bias[i0+i,:])[cA]
    float w0[IC];
    if constexpr (MODE == 0) {
        #pragma unroll
        for (int i = 0; i < IC; ++i) {
            float lg[N_C];
            #pragma unroll
            for (int c = 0; c < N_C; ++c) lg[c] = bias[(i0 + i) * N_C + c];
            float m = lg[0];
            #pragma unroll
            for (int c = 1; c < N_C; ++c) m = fmaxf(m, lg[c]);
            float ssum = 0.f;
            #pragma unroll
            for (int c = 0; c < N_C; ++c) { lg[c] = expf(lg[c] - m); ssum += lg[c]; }
            w0[i] = lg[cA] / ssum;
        }
    }
    // MODE 1: bias row for B1 (per-lane i1), hoisted out of the chunk loop
    float bias_r[N_C];
    if constexpr (MODE == 1) {
        #pragma unroll
        for (int c = 0; c < N_C; ++c) bias_r[c] = bias[(i0 + i1) * N_C + c];
    }

    for (int ch = 0; ch < 2; ++ch) {
        const int bbase = b0 + ch * BCH;

        // ---- stage x (and osum) into LDS ----
        if (t < 128) {
            const int sb = t >> 4, r = t & 15;
            const int il = r >> 1, hf = r & 1;
            *(float4*)&xl[(sb * IC + il) * 8 + hf * 4] =
                *(const float4*)(inp + ((size_t)(bbase + sb) * N_I + i0 + il) * 8 + hf * 4);
        }
        if constexpr (MODE == 1) {
            *(float4*)&osl[iA * CV + (cA * 4 + vqA) * 4] =   // iA=sb, (cA,vqA)=q 0..39
                *(const float4*)(osum + (size_t)(bbase + iA) * CV + (cA * 4 + vqA) * 4);
        }
        __syncthreads();

        // ---- phase A: u_tile[b][iA][cA*16+vqA*4..] = sum_d x*W ----
        #pragma unroll
        for (int b = 0; b < BCH; ++b) {
            const float4 xa = *(const float4*)&xl[(b * IC + iA) * 8];
            const float4 xb = *(const float4*)&xl[(b * IC + iA) * 8 + 4];
            const float xs[8] = {xa.x, xa.y, xa.z, xa.w, xb.x, xb.y, xb.z, xb.w};
            float4 acc = {0.f, 0.f, 0.f, 0.f};
            #pragma unroll
            for (int d = 0; d < 8; ++d) {
                acc.x += xs[d] * Wr[d].x;
                acc.y += xs[d] * Wr[d].y;
                acc.z += xs[d] * Wr[d].z;
                acc.w += xs[d] * Wr[d].w;
            }
            *(float4*)&u_tile[(b * IC + iA) * UPAD + cA * 16 + vqA * 4] = acc;
        }
        __syncthreads();

        // ---- phase B1 (MODE 1): logits -> softmax -> wt ----
        if constexpr (MODE == 1) {
            if (t < 256) {
                float lg[N_C];
                #pragma unroll
                for (int c = 0; c < N_C; ++c) {
                    const float4 u4 = *(const float4*)&u_tile[(b1 * IC + i1) * UPAD + c * 16 + vq1 * 4];
                    const float4 o4 = *(const float4*)&osl[b1 * CV + c * 16 + vq1 * 4];
                    float d = u4.x * o4.x + u4.y * o4.y + u4.z * o4.z + u4.w * o4.w;
                    d += __shfl_xor(d, 1);
                    d += __shfl_xor(d, 2);
                    lg[c] = d + bias_r[c];
                }
                float m = lg[0];
                #pragma unroll
                for (int c = 1; c < N_C; ++c) m = fmaxf(m, lg[c]);
                float ssum = 0.f;
                #pragma unroll
                for (int c = 0; c < N_C; ++c) { lg[c] = expf(lg[c] - m); ssum += lg[c]; }
                const float inv = 1.0f / ssum;
                if (vq1 == 0) {
                    #pragma unroll
                    for (int c = 0; c < N_C; ++c)
                        wt[(b1 * IC + i1) * N_C + c] = lg[c] * inv;
                }
            }
        }
        __syncthreads();

        // ---- phase B2: s partial over this i-chunk ----
        {
            float4 sp = {0.f, 0.f, 0.f, 0.f};
            #pragma unroll
            for (int i = 0; i < IC; ++i) {
                float wv;
                if constexpr (MODE == 1) wv = wt[(iA * IC + i) * N_C + cA];  // iA = bb here
                else                     wv = w0[i];
                const float4 u4 = *(const float4*)&u_tile[(iA * IC + i) * UPAD + cA * 16 + vqA * 4];
                sp.x += wv * u4.x;
                sp.y += wv * u4.y;
                sp.z += wv * u4.z;
                sp.w += wv * u4.w;
            }
            *(float4*)(s_part + ((size_t)ic * N_B + (bbase + iA)) * CV + cA * 16 + vqA * 4) = sp;
        }
        __syncthreads();
    }
}

// grid 256 (b), block (160,4): reduce 144 partials, squash, emit
template <int OM>  // 0: dst = squash; 1: dst = osum_in + squash; 2: dst = out (squash)
__global__ void k_squash(const float* __restrict__ s_part,
                         const float* __restrict__ osum_in,
                         float* __restrict__ dst) {
    const int b = blockIdx.x;
    const int t = threadIdx.x;   // 0..159  (c*16+v)
    const int y = threadIdx.y;   // 0..3
    __shared__ float red[4][CV];

    float s = 0.f;
    for (int j = 0; j < N_ICH / 4; ++j) {
        const int k = y * (N_ICH / 4) + j;
        s += s_part[((size_t)k * N_B + b) * CV + t];
    }
    red[y][t] = s;
    __syncthreads();

    if (y == 0) {
        s = red[0][t] + red[1][t] + red[2][t] + red[3][t];
        float sq = s * s;
        sq += __shfl_xor(sq, 1);
        sq += __shfl_xor(sq, 2);
        sq += __shfl_xor(sq, 4);
        sq += __shfl_xor(sq, 8);
        const float o = s * (sq / (1.0f + sq)) / sqrtf(sq + 1e-7f);
        if constexpr (OM == 1) dst[b * CV + t] = osum_in[b * CV + t] + o;
        else                   dst[b * CV + t] = o;
    }
}

extern "C" void kernel_launch(void* const* d_in, const int* in_sizes, int n_in,
                              void* d_out, int out_size, void* d_ws, size_t ws_size,
                              hipStream_t stream) {
    (void)in_sizes; (void)n_in; (void)out_size; (void)ws_size;
    const float* inp  = (const float*)d_in[0];
    const float* W    = (const float*)d_in[1];
    const float* bias = (const float*)d_in[2];
    float* out = (float*)d_out;

    float* s_part = (float*)d_ws;                        // 144*256*160*4 = 23,592,960 B
    float* osum_a = s_part + (size_t)N_ICH * N_B * CV;   // 163,840 B  (= out1)
    float* osum_b = osum_a + (size_t)N_B * CV;           // 163,840 B  (= out1+out2)

    const dim3 sq_blk(CV, 4);

    k_pass<0><<<N_ICH * NBS, 320, 0, stream>>>(inp, W, bias, nullptr, s_part);
    k_squash<0><<<N_B, sq_blk, 0, stream>>>(s_part, nullptr, osum_a);
    k_pass<1><<<N_ICH * NBS, 320, 0, stream>>>(inp, W, bias, osum_a, s_part);
    k_squash<1><<<N_B, sq_blk, 0, stream>>>(s_part, osum_a, osum_b);
    k_pass<1><<<N_ICH * NBS, 320, 0, stream>>>(inp, W, bias, osum_b, s_part);
    k_squash<2><<<N_B, sq_blk, 0, stream>>>(s_part, nullptr, out);
}

// Round 4
// 193.292 us; speedup vs baseline: 1.1343x; 1.1343x over previous
//
#include <hip/hip_runtime.h>
#include <hip/hip_fp16.h>

// CapsuleLayer dynamic routing, MI355X — materialize u_hat ONCE in fp16 (94.4MB,
// L3-resident), then 3 streaming routing passes + tiny squash kernels.
//
//   u_hat[b,i,c,v] = sum_d x[b,i,d] W[i,c,d,v]          (fp32 compute, fp16 store)
//   pass r: c_r = softmax_c(bias + dot_v(u_hat, osum_{r-1})), osum_0 = 0
//   s_r[b,c,v] = sum_i c_r * u_hat;  out_r = squash(s_r);  osum_r = sum out
//
// Adaptive batch segmentation if ws_size is small (bn = 256 -> 95.4MB needed).

#define N_I  1152
#define N_C  10
#define N_Bt 256
#define CV   160    // N_C * 16
#define NSPL 4      // i-splits per routing pass
#define ISPL 288    // N_I / NSPL

// ---- K1: u_hat (fp16). grid (1152, bn/64), block 320 = 8 bsub x 40 (c,vq) ----
__global__ __launch_bounds__(320) void k_uhat(const float* __restrict__ inp,
                                              const float* __restrict__ W,
                                              __half* __restrict__ uhat,
                                              int b_base, int sn) {
    const int i   = blockIdx.x;
    const int bl0 = blockIdx.y * 64;
    __shared__ float Wl[N_C * 132];   // pad c-stride 128->132 (bank spread)
    {
        const int t4 = threadIdx.x * 4;                 // 0..1276
        const float4 w4 = *reinterpret_cast<const float4*>(W + (size_t)i * 1280 + t4);
        const int c = t4 >> 7, rem = t4 & 127;
        *reinterpret_cast<float4*>(&Wl[c * 132 + rem]) = w4;
    }
    __syncthreads();
    const int cv  = threadIdx.x % 40;
    const int bs0 = threadIdx.x / 40;
    const int c = cv >> 2, vq = cv & 3;
    const float* wbase = &Wl[c * 132 + vq * 4];
    float4 Wr[8];
    #pragma unroll
    for (int d = 0; d < 8; ++d) Wr[d] = *reinterpret_cast<const float4*>(wbase + d * 16);

    for (int s = 0; s < sn; ++s) {
        const int bo = bl0 + s * 8 + bs0;               // local b
        const float* ib = inp + ((size_t)(b_base + bo) * N_I + i) * 8;
        const float4 xa = *reinterpret_cast<const float4*>(ib);
        const float4 xb = *reinterpret_cast<const float4*>(ib + 4);
        float4 acc = {0.f, 0.f, 0.f, 0.f};
        acc.x = xa.x * Wr[0].x; acc.y = xa.x * Wr[0].y;
        acc.z = xa.x * Wr[0].z; acc.w = xa.x * Wr[0].w;
        acc.x += xa.y * Wr[1].x; acc.y += xa.y * Wr[1].y;
        acc.z += xa.y * Wr[1].z; acc.w += xa.y * Wr[1].w;
        acc.x += xa.z * Wr[2].x; acc.y += xa.z * Wr[2].y;
        acc.z += xa.z * Wr[2].z; acc.w += xa.z * Wr[2].w;
        acc.x += xa.w * Wr[3].x; acc.y += xa.w * Wr[3].y;
        acc.z += xa.w * Wr[3].z; acc.w += xa.w * Wr[3].w;
        acc.x += xb.x * Wr[4].x; acc.y += xb.x * Wr[4].y;
        acc.z += xb.x * Wr[4].z; acc.w += xb.x * Wr[4].w;
        acc.x += xb.y * Wr[5].x; acc.y += xb.y * Wr[5].y;
        acc.z += xb.y * Wr[5].z; acc.w += xb.y * Wr[5].w;
        acc.x += xb.z * Wr[6].x; acc.y += xb.z * Wr[6].y;
        acc.z += xb.z * Wr[6].z; acc.w += xb.z * Wr[6].w;
        acc.x += xb.w * Wr[7].x; acc.y += xb.w * Wr[7].y;
        acc.z += xb.w * Wr[7].z; acc.w += xb.w * Wr[7].w;
        union { __half2 h[2]; uint2 u; } pk;
        pk.h[0] = __floats2half2_rn(acc.x, acc.y);
        pk.h[1] = __floats2half2_rn(acc.z, acc.w);
        *reinterpret_cast<uint2*>(uhat + ((size_t)bo * N_I + i) * CV + cv * 4) = pk.u;
    }
}

// ---- R: routing pass. grid bn*4, block 576 = 144 ig x 4 vq; 2 i per lane ----
template <int MODE>  // 0: logits = bias only; 1: bias + dot(u, osum)
__global__ __launch_bounds__(576) void k_route(const __half* __restrict__ uhat,
                                               const float* __restrict__ bias,
                                               const float* __restrict__ osum,
                                               float* __restrict__ s_part) {
    const int bl  = blockIdx.x >> 2;
    const int spl = blockIdx.x & 3;
    const int t  = threadIdx.x;
    const int vq = t & 3;
    const int ig = t >> 2;            // 0..143
    __shared__ float sred[9 * CV];

    float4 os[N_C];
    if constexpr (MODE) {
        const float* ob = osum + bl * CV;
        #pragma unroll
        for (int c = 0; c < N_C; ++c)
            os[c] = *reinterpret_cast<const float4*>(ob + c * 16 + vq * 4);
    }

    float4 sp[N_C];
    #pragma unroll
    for (int c = 0; c < N_C; ++c) sp[c] = {0.f, 0.f, 0.f, 0.f};

    #pragma unroll
    for (int ii = 0; ii < 2; ++ii) {
        const int i = spl * ISPL + ii * 144 + ig;
        const __half* up = uhat + ((size_t)bl * N_I + i) * CV + vq * 4;
        float4 u[N_C];
        #pragma unroll
        for (int c = 0; c < N_C; ++c) {
            union { uint2 u2; __half2 h[2]; } r;
            r.u2 = *reinterpret_cast<const uint2*>(up + c * 16);
            const float2 f0 = __half22float2(r.h[0]);
            const float2 f1 = __half22float2(r.h[1]);
            u[c] = {f0.x, f0.y, f1.x, f1.y};
        }
        float lg[N_C];
        #pragma unroll
        for (int c = 0; c < N_C; ++c) {
            float dd = 0.f;
            if constexpr (MODE) {
                dd = u[c].x * os[c].x + u[c].y * os[c].y +
                     u[c].z * os[c].z + u[c].w * os[c].w;
                dd += __shfl_xor(dd, 1);
                dd += __shfl_xor(dd, 2);
            }
            lg[c] = dd + bias[i * N_C + c];
        }
        float m = lg[0];
        #pragma unroll
        for (int c = 1; c < N_C; ++c) m = fmaxf(m, lg[c]);
        float ssum = 0.f;
        #pragma unroll
        for (int c = 0; c < N_C; ++c) { lg[c] = __expf(lg[c] - m); ssum += lg[c]; }
        const float inv = 1.0f / ssum;
        #pragma unroll
        for (int c = 0; c < N_C; ++c) {
            const float wc = lg[c] * inv;
            sp[c].x += wc * u[c].x;
            sp[c].y += wc * u[c].y;
            sp[c].z += wc * u[c].z;
            sp[c].w += wc * u[c].w;
        }
    }

    // reduce over the 16 ig's within each wave (lane bits 2..5)
    #pragma unroll
    for (int c = 0; c < N_C; ++c) {
        #pragma unroll
        for (int off = 4; off <= 32; off <<= 1) {
            sp[c].x += __shfl_xor(sp[c].x, off);
            sp[c].y += __shfl_xor(sp[c].y, off);
            sp[c].z += __shfl_xor(sp[c].z, off);
            sp[c].w += __shfl_xor(sp[c].w, off);
        }
    }
    const int lane = t & 63, wv = t >> 6;   // 9 waves
    if (lane < 4) {
        #pragma unroll
        for (int c = 0; c < N_C; ++c)
            *reinterpret_cast<float4*>(&sred[wv * CV + lane * 40 + c * 4]) = sp[c];
    }
    __syncthreads();
    if (t < CV) {
        const int cc = t >> 4, v = t & 15, vq2 = v >> 2, j = v & 3;
        float s = 0.f;
        #pragma unroll
        for (int w = 0; w < 9; ++w) s += sred[w * CV + vq2 * 40 + cc * 4 + j];
        s_part[((size_t)bl * NSPL + spl) * CV + t] = s;   // t = c*16+v
    }
}

// ---- squash: grid bn, block 160 ----
template <int OM>  // 0: dst=squash; 1: dst=osum_in+squash; 2: dst=out (global b)
__global__ __launch_bounds__(160) void k_squash(const float* __restrict__ s_part,
                                                const float* __restrict__ osum_in,
                                                float* __restrict__ dst, int b_off) {
    const int bl = blockIdx.x;
    const int t  = threadIdx.x;   // c*16+v
    float s = 0.f;
    #pragma unroll
    for (int k = 0; k < NSPL; ++k) s += s_part[((size_t)bl * NSPL + k) * CV + t];
    float sq = s * s;
    sq += __shfl_xor(sq, 1);
    sq += __shfl_xor(sq, 2);
    sq += __shfl_xor(sq, 4);
    sq += __shfl_xor(sq, 8);
    const float o = s * (sq / (1.0f + sq)) / sqrtf(sq + 1e-7f);
    if constexpr (OM == 1)      dst[bl * CV + t] = osum_in[bl * CV + t] + o;
    else if constexpr (OM == 2) dst[((size_t)(b_off + bl)) * CV + t] = o;
    else                        dst[bl * CV + t] = o;
}

extern "C" void kernel_launch(void* const* d_in, const int* in_sizes, int n_in,
                              void* d_out, int out_size, void* d_ws, size_t ws_size,
                              hipStream_t stream) {
    (void)in_sizes; (void)n_in; (void)out_size;
    const float* inp  = (const float*)d_in[0];
    const float* W    = (const float*)d_in[1];
    const float* bias = (const float*)d_in[2];
    float* out = (float*)d_out;

    // pick largest batch segment that fits ws
    int bn = 256;
    while (bn > 32) {
        size_t need = (size_t)bn * N_I * CV * 2     // uhat fp16
                    + (size_t)bn * NSPL * CV * 4    // s_part
                    + 2ull * bn * CV * 4;           // osum_a/b
        if (need <= ws_size) break;
        bn >>= 1;
    }

    __half* uhat  = (__half*)d_ws;
    float* s_part = (float*)((char*)d_ws + (size_t)bn * N_I * CV * 2);
    float* osum_a = s_part + (size_t)bn * NSPL * CV;
    float* osum_b = osum_a + (size_t)bn * CV;

    const int sn = (bn < 64 ? bn : 64) >> 3;               // b's per block / 8
    const dim3 gu(N_I, (unsigned)((bn + 63) / 64));

    for (int b0 = 0; b0 < N_Bt; b0 += bn) {
        k_uhat<<<gu, 320, 0, stream>>>(inp, W, uhat, b0, sn);
        k_route<0><<<bn * NSPL, 576, 0, stream>>>(uhat, bias, nullptr, s_part);
        k_squash<0><<<bn, 160, 0, stream>>>(s_part, nullptr, osum_a, 0);
        k_route<1><<<bn * NSPL, 576, 0, stream>>>(uhat, bias, osum_a, s_part);
        k_squash<1><<<bn, 160, 0, stream>>>(s_part, osum_a, osum_b, 0);
        k_route<1><<<bn * NSPL, 576, 0, stream>>>(uhat, bias, osum_b, s_part);
        k_squash<2><<<bn, 160, 0, stream>>>(s_part, nullptr, out, b0);
    }
}